// Round 14
// baseline (58.253 us; speedup 1.0000x reference)
//
#include <hip/hip_runtime.h>

typedef __bf16 bf16x8 __attribute__((ext_vector_type(8)));
typedef __bf16 bf16x4 __attribute__((ext_vector_type(4)));
typedef float f32x4 __attribute__((ext_vector_type(4)));
typedef unsigned short u16x8 __attribute__((ext_vector_type(8)));

union FragU { u16x8 u; bf16x8 b; };
union PackU { bf16x4 v; unsigned long long q; };

__device__ __forceinline__ unsigned short bfbits(float f) {
  __bf16 h = (__bf16)f;
  union { __bf16 h; unsigned short s; } cv; cv.h = h;
  return cv.s;
}

#define MFMA16(a, b, c) __builtin_amdgcn_mfma_f32_16x16x32_bf16((a), (b), (c), 0, 0, 0)

// 0.125 (1/sqrt(64)) * log2(e): softmax done in base-2
#define QSCALE 0.18033688011112042f

// ---------------- W -> fragment-order bf16: WF[m][c][t][lane][8] ----------------
__global__ __launch_bounds__(256) void wt_kernel(
    const float* __restrict__ Wq, const float* __restrict__ Wk, const float* __restrict__ Wv,
    unsigned short* __restrict__ WF)
{
  const int m = blockIdx.x >> 5;         // 0..2
  const int c = blockIdx.x & 31;         // 0..31
  const float* W = (m == 0) ? Wq : ((m == 1) ? Wk : Wv);
  const int t = threadIdx.x >> 6;
  const int lane = threadIdx.x & 63;
  const int l15 = lane & 15;
  const int g = lane >> 4;
  unsigned short* dst = WF + ((((size_t)m * 32 + c) * 4 + t) * 64 + lane) * 8;
#pragma unroll
  for (int e = 0; e < 8; ++e)
    dst[e] = bfbits(W[(size_t)(32 * c + 8 * g + e) * 64 + (16 * t + l15)]);
}

// ---------------- fused QKV projection: k-split-2 x counted-vmcnt W-DMA ----------------
// grid 512 x 256 thr; block = 32 rows; wave (rg=wid&1, kh=wid>>1) computes rows
// rg*16..+15 over K-chunk [kh*512, kh*512+512) = 16 c-iters. W staged via
// global_load_lds into per-kh mod-3 LDS ring (72 KB total -> 2 blocks/CU =
// 2 waves/SIMD), 2 tiles ahead, per-iter exact counted vmcnt (never 0 mid-loop).
// s_barrier per iter: ring overwrite ordered after both pair-waves' reads.
// fp32 partial combine in reused LDS; R8-proven split epilogue.
__global__ __launch_bounds__(256, 2) void proj_kernel(
    const float* __restrict__ x, const unsigned short* __restrict__ WF,
    const float* __restrict__ bq, const float* __restrict__ bk, const float* __restrict__ bv,
    unsigned short* __restrict__ Qb, unsigned short* __restrict__ KF,
    unsigned short* __restrict__ VF)
{
  __shared__ __align__(16) unsigned short ldsW[2][3][6144];   // [kh][slot][12KB] = 72 KB
  const int tid = threadIdx.x;
  const int lane = tid & 63;
  const int wid = tid >> 6;               // 0..3
  const int rg = wid & 1;
  const int kh = wid >> 1;
  const int l15 = lane & 15;
  const int g = lane >> 4;
  const int row0 = blockIdx.x * 32 + rg * 16;
  const int c0 = kh * 16;

  f32x4 accQ[4], accK[4], accV[4];
  const f32x4 zero = {0.f, 0.f, 0.f, 0.f};
#pragma unroll
  for (int i = 0; i < 4; ++i) { accQ[i] = zero; accK[i] = zero; accV[i] = zero; }

  const float* xrow = x + (size_t)(row0 + l15) * 1024;
  f32x4 xx0[4], xx1[4];

  // wave stages its 6 frags (f = rg*6+j; m=f>>2, t=f&3) of tile CC -> ldsW[kh][CC%3]
#define WDMA(CC) { const int sl_ = (CC) % 3; \
    _Pragma("unroll") for (int j_ = 0; j_ < 6; ++j_) { \
      const int f_ = rg * 6 + j_; \
      const int m_ = f_ >> 2, t_ = f_ & 3; \
      const unsigned short* gs_ = WF + ((((size_t)m_ * 32 + (CC)) * 4 + t_) * 64 + lane) * 8; \
      __builtin_amdgcn_global_load_lds( \
          (const __attribute__((address_space(1))) void*)gs_, \
          (__attribute__((address_space(3))) void*)&ldsW[kh][sl_][f_ * 512], \
          16, 0, 0); } }

#define PLDX(XB, C) { xx0[XB] = *(const f32x4*)(xrow + 32 * (C) + 8 * g); \
                      xx1[XB] = *(const f32x4*)(xrow + 32 * (C) + 8 * g + 4); }

#define SUBIT(CC, KK, WIMM, DOW, DOX) { \
    asm volatile("s_waitcnt vmcnt(" #WIMM ")" ::: "memory"); \
    __builtin_amdgcn_s_barrier(); \
    __builtin_amdgcn_sched_barrier(0); \
    if (DOW) WDMA((CC) + 2); \
    FragU xf; \
    _Pragma("unroll") for (int i_ = 0; i_ < 4; ++i_) { \
      xf.b[i_] = (__bf16)xx0[KK][i_]; xf.b[4 + i_] = (__bf16)xx1[KK][i_]; } \
    if (DOX) PLDX(KK, (CC) + 4); \
    { const int rs_ = (CC) % 3; \
      _Pragma("unroll") for (int t = 0; t < 4; ++t) { \
        const bf16x8 wq_ = *(const bf16x8*)&ldsW[kh][rs_][(0 * 4 + t) * 512 + lane * 8]; \
        const bf16x8 wk_ = *(const bf16x8*)&ldsW[kh][rs_][(1 * 4 + t) * 512 + lane * 8]; \
        const bf16x8 wv_ = *(const bf16x8*)&ldsW[kh][rs_][(2 * 4 + t) * 512 + lane * 8]; \
        accQ[t] = MFMA16(xf.b, wq_, accQ[t]); \
        accK[t] = MFMA16(xf.b, wk_, accK[t]); \
        accV[t] = MFMA16(wv_, xf.b, accV[t]); } } }

  // prologue: x slots 0..3 (8 ops) then W tiles c0, c0+1 (12 ops) -> 20 in flight
  PLDX(0, c0 + 0) PLDX(1, c0 + 1) PLDX(2, c0 + 2) PLDX(3, c0 + 3)
  WDMA(c0)
  __builtin_amdgcn_sched_barrier(0);
  WDMA(c0 + 1)

  // 16 iters; vmcnt immediates exact from op-position arithmetic (8 ops/iter steady)
  SUBIT(c0 + 0,  0, 6,  1, 1)
  SUBIT(c0 + 1,  1, 8,  1, 1)
  SUBIT(c0 + 2,  2, 10, 1, 1)
  SUBIT(c0 + 3,  3, 10, 1, 1)
  SUBIT(c0 + 4,  0, 10, 1, 1)
  SUBIT(c0 + 5,  1, 10, 1, 1)
  SUBIT(c0 + 6,  2, 10, 1, 1)
  SUBIT(c0 + 7,  3, 10, 1, 1)
  SUBIT(c0 + 8,  0, 10, 1, 1)
  SUBIT(c0 + 9,  1, 10, 1, 1)
  SUBIT(c0 + 10, 2, 10, 1, 1)
  SUBIT(c0 + 11, 3, 10, 1, 1)
  SUBIT(c0 + 12, 0, 10, 1, 0)
  SUBIT(c0 + 13, 1, 8,  1, 0)
  SUBIT(c0 + 14, 2, 6,  0, 0)
  SUBIT(c0 + 15, 3, 0,  0, 0)

  // ---- fp32 partial combine (reuse ldsW) ----
  __syncthreads();
  f32x4* part = (f32x4*)ldsW;   // part[(kh*2+rg)*12 + m*4 + t][lane] : 48 KB of 72
#pragma unroll
  for (int t = 0; t < 4; ++t) {
    part[(size_t)((kh * 2 + rg) * 12 + 0 * 4 + t) * 64 + lane] = accQ[t];
    part[(size_t)((kh * 2 + rg) * 12 + 1 * 4 + t) * 64 + lane] = accK[t];
    part[(size_t)((kh * 2 + rg) * 12 + 2 * 4 + t) * 64 + lane] = accV[t];
  }
  __syncthreads();

  // epilogue tasks: w0/w1 -> Q,V of rg=wid&1 ; w2/w3 -> K of rg=wid&1
  const int erg = wid & 1;
  const int b = blockIdx.x >> 7;
  const int q0 = (blockIdx.x * 32 + erg * 16) & 4095;
  const int kt = q0 >> 6;
  const int r16 = (q0 >> 4) & 3;
  f32x4 s[4];
  if (wid < 2) {
    // ---- Q ----
#pragma unroll
    for (int t = 0; t < 4; ++t) {
      const f32x4 p0 = part[(size_t)((0 * 2 + erg) * 12 + 0 * 4 + t) * 64 + lane];
      const f32x4 p1 = part[(size_t)((1 * 2 + erg) * 12 + 0 * 4 + t) * 64 + lane];
#pragma unroll
      for (int i = 0; i < 4; ++i) s[t][i] = p0[i] + p1[i];
    }
    unsigned short* Qbase = Qb + (size_t)b * 4096 * 64;
#pragma unroll
    for (int t = 0; t < 4; ++t) {
      const float bqv = bq[16 * t + l15];
#pragma unroll
      for (int r = 0; r < 4; ++r)
        Qbase[(size_t)(q0 + 4 * g + r) * 64 + 16 * t + l15] =
            bfbits((s[t][r] + bqv) * QSCALE);
    }
    // ---- V ----
#pragma unroll
    for (int t = 0; t < 4; ++t) {
      const f32x4 p0 = part[(size_t)((0 * 2 + erg) * 12 + 2 * 4 + t) * 64 + lane];
      const f32x4 p1 = part[(size_t)((1 * 2 + erg) * 12 + 2 * 4 + t) * 64 + lane];
#pragma unroll
      for (int i = 0; i < 4; ++i) s[t][i] = p0[i] + p1[i];
    }
    unsigned short* VFb = VF + ((size_t)b * 64 + kt) * 4096;
#pragma unroll
    for (int t = 0; t < 4; ++t) {
#pragma unroll
      for (int r = 0; r < 4; ++r) {
        const int hv = 16 * t + 4 * g + r;
        VFb[(size_t)((t * 2 + (r16 >> 1)) * 64 + (r16 & 1) * 32 + (l15 >> 3) * 16 + 4 * g + r) * 8 +
            (l15 & 7)] = bfbits(s[t][r] + bv[hv]);
      }
    }
  } else {
    // ---- K ----
#pragma unroll
    for (int t = 0; t < 4; ++t) {
      const f32x4 p0 = part[(size_t)((0 * 2 + erg) * 12 + 1 * 4 + t) * 64 + lane];
      const f32x4 p1 = part[(size_t)((1 * 2 + erg) * 12 + 1 * 4 + t) * 64 + lane];
#pragma unroll
      for (int i = 0; i < 4; ++i) s[t][i] = p0[i] + p1[i];
    }
    unsigned short* KFb = KF + ((size_t)b * 64 + kt) * 4096;
#pragma unroll
    for (int t = 0; t < 4; ++t) {
      const float bkv = bk[16 * t + l15];
#pragma unroll
      for (int r = 0; r < 4; ++r)
        KFb[(size_t)((r16 * 2 + (t >> 1)) * 64 + (t & 1) * 32 + (l15 >> 3) * 16 + 4 * g + r) * 8 +
            (l15 & 7)] = bfbits(s[t][r] + bkv);
    }
  }
}

// ---------------- flash attention: 32 q-rows/wave, k-split 4 + setprio ----------------
__global__ __launch_bounds__(256, 2) void flash_kernel(
    const unsigned short* __restrict__ Qb, const unsigned short* __restrict__ KF,
    const unsigned short* __restrict__ VF, float* __restrict__ out)
{
  __shared__ __align__(16) unsigned char lds[36864];
  const int tid = threadIdx.x;
  const int lane = tid & 63;
  const int w = tid >> 6;                 // 0..3 = k-split
  const int l15 = lane & 15;
  const int g = lane >> 4;
  const int bid = blockIdx.x;
  const int xcd = bid & 7;
  const int b = xcd >> 1;
  const int qt = (bid >> 3) * 2 + (xcd & 1);   // 0..127
  const int q0 = qt * 32;

  const unsigned short* Qp = Qb + (size_t)b * 4096 * 64;
  const unsigned short* KFb = KF + (size_t)b * 262144;
  const unsigned short* VFb = VF + (size_t)b * 262144;

  const bf16x8 qfA0 = *(const bf16x8*)(Qp + (size_t)(q0 + l15) * 64 + 8 * g);
  const bf16x8 qfA1 = *(const bf16x8*)(Qp + (size_t)(q0 + l15) * 64 + 32 + 8 * g);
  const bf16x8 qfB0 = *(const bf16x8*)(Qp + (size_t)(q0 + 16 + l15) * 64 + 8 * g);
  const bf16x8 qfB1 = *(const bf16x8*)(Qp + (size_t)(q0 + 16 + l15) * 64 + 32 + 8 * g);

  f32x4 O_A[4], O_B[4];
  const f32x4 zero = {0.f, 0.f, 0.f, 0.f};
#pragma unroll
  for (int i = 0; i < 4; ++i) { O_A[i] = zero; O_B[i] = zero; }
  float mA = -INFINITY, lA = 0.f, mB = -INFINITY, lB = 0.f;
  unsigned short* PwA = (unsigned short*)lds + (w * 2 + 0) * 1152;
  unsigned short* PwB = (unsigned short*)lds + (w * 2 + 1) * 1152;

#define SM_HALF(S, mvar, lvar, OA, PW) { \
  float mt = fmaxf(fmaxf(S[0][0], S[0][1]), fmaxf(S[0][2], S[0][3])); \
  _Pragma("unroll") for (int t = 1; t < 4; ++t) \
    _Pragma("unroll") for (int r = 0; r < 4; ++r) mt = fmaxf(mt, S[t][r]); \
  mt = fmaxf(mt, __shfl_xor(mt, 16)); \
  mt = fmaxf(mt, __shfl_xor(mt, 32)); \
  if (!__all(mt <= mvar + 8.0f)) { \
    const float mnew = fmaxf(mvar, mt); \
    const float alpha = __builtin_amdgcn_exp2f(mvar - mnew); \
    mvar = mnew; lvar *= alpha; \
    _Pragma("unroll") for (int r = 0; r < 4; ++r) { \
      const float ar = __shfl(alpha, 4 * g + r); \
      OA[0][r] *= ar; OA[1][r] *= ar; OA[2][r] *= ar; OA[3][r] *= ar; } \
  } \
  float ps = 0.f; \
  _Pragma("unroll") for (int t = 0; t < 4; ++t) { \
    const float p0 = __builtin_amdgcn_exp2f(S[t][0] - mvar); \
    const float p1 = __builtin_amdgcn_exp2f(S[t][1] - mvar); \
    const float p2 = __builtin_amdgcn_exp2f(S[t][2] - mvar); \
    const float p3 = __builtin_amdgcn_exp2f(S[t][3] - mvar); \
    ps += (p0 + p1) + (p2 + p3); \
    PackU pk_; pk_.v[0] = (__bf16)p0; pk_.v[1] = (__bf16)p1; \
    pk_.v[2] = (__bf16)p2; pk_.v[3] = (__bf16)p3; \
    *(unsigned long long*)((PW) + l15 * 72 + 16 * t + 4 * g) = pk_.q; } \
  ps += __shfl_xor(ps, 16); \
  ps += __shfl_xor(ps, 32); \
  lvar += ps; }

#pragma unroll 1
  for (int kt = w; kt < 64; kt += 4) {
    const unsigned short* Kt = KFb + kt * 4096;
    const unsigned short* Vt = VFb + kt * 4096;
    bf16x8 kf[8], vf[8];
#pragma unroll
    for (int j = 0; j < 8; ++j) kf[j] = *(const bf16x8*)(Kt + (j * 64 + lane) * 8);
#pragma unroll
    for (int j = 0; j < 8; ++j) vf[j] = *(const bf16x8*)(Vt + (j * 64 + lane) * 8);
    f32x4 S_A[4], S_B[4];
    __builtin_amdgcn_s_setprio(1);
#pragma unroll
    for (int t = 0; t < 4; ++t) {
      S_A[t] = zero;
      S_A[t] = MFMA16(kf[2 * t], qfA0, S_A[t]);
      S_A[t] = MFMA16(kf[2 * t + 1], qfA1, S_A[t]);
      S_B[t] = zero;
      S_B[t] = MFMA16(kf[2 * t], qfB0, S_B[t]);
      S_B[t] = MFMA16(kf[2 * t + 1], qfB1, S_B[t]);
    }
    __builtin_amdgcn_s_setprio(0);
    SM_HALF(S_A, mA, lA, O_A, PwA)
    SM_HALF(S_B, mB, lB, O_B, PwB)
    __builtin_amdgcn_s_setprio(1);
#pragma unroll
    for (int s = 0; s < 2; ++s) {
      const bf16x8 paA = *(const bf16x8*)(PwA + l15 * 72 + 32 * s + 8 * g);
      const bf16x8 paB = *(const bf16x8*)(PwB + l15 * 72 + 32 * s + 8 * g);
#pragma unroll
      for (int nt = 0; nt < 4; ++nt) {
        O_A[nt] = MFMA16(paA, vf[2 * nt + s], O_A[nt]);
        O_B[nt] = MFMA16(paB, vf[2 * nt + s], O_B[nt]);
      }
    }
    __builtin_amdgcn_s_setprio(0);
  }

  // ---- in-LDS combine of the 4 k-split partials ----
  __syncthreads();
  float* O_l = (float*)lds;                 // [8][16][68]
  float* mlp = (float*)(lds + 34816);       // [8][16][2]
#pragma unroll
  for (int nt = 0; nt < 4; ++nt)
#pragma unroll
    for (int r = 0; r < 4; ++r) {
      O_l[((w * 2 + 0) * 16 + 4 * g + r) * 68 + 16 * nt + l15] = O_A[nt][r];
      O_l[((w * 2 + 1) * 16 + 4 * g + r) * 68 + 16 * nt + l15] = O_B[nt][r];
    }
  if (g == 0) {
    mlp[((w * 2 + 0) * 16 + l15) * 2] = mA; mlp[((w * 2 + 0) * 16 + l15) * 2 + 1] = lA;
    mlp[((w * 2 + 1) * 16 + l15) * 2] = mB; mlp[((w * 2 + 1) * 16 + l15) * 2 + 1] = lB;
  }
  __syncthreads();

  const int q = tid >> 3;           // 0..31
  const int h0 = (tid & 7) * 8;     // 0..56
  const int qh = q >> 4, qr = q & 15;
  float M = -INFINITY;
#pragma unroll
  for (int s = 0; s < 4; ++s) M = fmaxf(M, mlp[((s * 2 + qh) * 16 + qr) * 2]);
  float L = 0.f;
  f32x4 a0 = zero, a1 = zero;
#pragma unroll
  for (int s = 0; s < 4; ++s) {
    const int rowi = (s * 2 + qh) * 16 + qr;
    const float wgt = __builtin_amdgcn_exp2f(mlp[rowi * 2] - M);
    L += wgt * mlp[rowi * 2 + 1];
    const f32x4 o0 = *(const f32x4*)&O_l[rowi * 68 + h0];
    const f32x4 o1 = *(const f32x4*)&O_l[rowi * 68 + h0 + 4];
#pragma unroll
    for (int i = 0; i < 4; ++i) { a0[i] += wgt * o0[i]; a1[i] += wgt * o1[i]; }
  }
  const float inv = 1.0f / L;
  float* ob = out + ((size_t)b * 4096 + qt * 32 + q) * 64 + h0;
  f32x4 r0 = {a0[0] * inv, a0[1] * inv, a0[2] * inv, a0[3] * inv};
  f32x4 r1 = {a1[0] * inv, a1[1] * inv, a1[2] * inv, a1[3] * inv};
  *(f32x4*)ob = r0;
  *(f32x4*)(ob + 4) = r1;
}

extern "C" void kernel_launch(void* const* d_in, const int* in_sizes, int n_in,
                              void* d_out, int out_size, void* d_ws, size_t ws_size,
                              hipStream_t stream) {
  const float* x  = (const float*)d_in[0];
  const float* Wq = (const float*)d_in[1];
  const float* bq = (const float*)d_in[2];
  const float* Wk = (const float*)d_in[3];
  const float* bk = (const float*)d_in[4];
  const float* Wv = (const float*)d_in[5];
  const float* bv = (const float*)d_in[6];

  char* ws = (char*)d_ws;
  unsigned short* WF = (unsigned short*)ws;                              // 384 KB
  unsigned short* Qb = (unsigned short*)(ws + (512u << 10));             // 2 MB
  unsigned short* KF = (unsigned short*)(ws + (512u << 10) + (2u << 20));// 2 MB
  unsigned short* VF = (unsigned short*)(ws + (512u << 10) + (4u << 20));// 2 MB
  float* out = (float*)d_out;

  hipLaunchKernelGGL(wt_kernel,    dim3(96),  dim3(256), 0, stream, Wq, Wk, Wv, WF);
  hipLaunchKernelGGL(proj_kernel,  dim3(512), dim3(256), 0, stream, x, WF, bq, bk, bv, Qb, KF, VF);
  hipLaunchKernelGGL(flash_kernel, dim3(512), dim3(256), 0, stream, Qb, KF, VF, out);
}

// Round 15
// 55.159 us; speedup vs baseline: 1.0561x; 1.0561x over previous
//
#include <hip/hip_runtime.h>

typedef __bf16 bf16x8 __attribute__((ext_vector_type(8)));
typedef __bf16 bf16x4 __attribute__((ext_vector_type(4)));
typedef float f32x4 __attribute__((ext_vector_type(4)));
typedef unsigned short u16x8 __attribute__((ext_vector_type(8)));

union FragU { u16x8 u; bf16x8 b; };
union PackU { bf16x4 v; unsigned long long q; };

__device__ __forceinline__ unsigned short bfbits(float f) {
  __bf16 h = (__bf16)f;
  union { __bf16 h; unsigned short s; } cv; cv.h = h;
  return cv.s;
}

#define MFMA16(a, b, c) __builtin_amdgcn_mfma_f32_16x16x32_bf16((a), (b), (c), 0, 0, 0)

// 0.125 (1/sqrt(64)) * log2(e): softmax done in base-2
#define QSCALE 0.18033688011112042f

// ---------------- W -> fragment-order bf16: WF[m][c][t][lane][8] ----------------
__global__ __launch_bounds__(256) void wt_kernel(
    const float* __restrict__ Wq, const float* __restrict__ Wk, const float* __restrict__ Wv,
    unsigned short* __restrict__ WF)
{
  const int m = blockIdx.x >> 5;         // 0..2
  const int c = blockIdx.x & 31;         // 0..31
  const float* W = (m == 0) ? Wq : ((m == 1) ? Wk : Wv);
  const int t = threadIdx.x >> 6;
  const int lane = threadIdx.x & 63;
  const int l15 = lane & 15;
  const int g = lane >> 4;
  unsigned short* dst = WF + ((((size_t)m * 32 + c) * 4 + t) * 64 + lane) * 8;
#pragma unroll
  for (int e = 0; e < 8; ++e)
    dst[e] = bfbits(W[(size_t)(32 * c + 8 * g + e) * 64 + (16 * t + l15)]);
}

// ---------------- fused QKV projection: counted-vmcnt pipelined W-DMA (R13-proven) ----------------
__global__ __launch_bounds__(256, 1) void proj_kernel(
    const float* __restrict__ x, const unsigned short* __restrict__ WF,
    const float* __restrict__ bq, const float* __restrict__ bk, const float* __restrict__ bv,
    unsigned short* __restrict__ Qb, unsigned short* __restrict__ KF,
    unsigned short* __restrict__ VF)
{
  __shared__ __align__(16) unsigned short ldsW[4][6144];   // 4 slots x 12 KB = 48 KB
  const int tid = threadIdx.x;
  const int lane = tid & 63;
  const int wid = tid >> 6;               // 0..3
  const int l15 = lane & 15;
  const int g = lane >> 4;
  const int row0 = blockIdx.x * 64 + wid * 16;

  f32x4 accQ[4], accK[4], accV[4];
  const f32x4 zero = {0.f, 0.f, 0.f, 0.f};
#pragma unroll
  for (int i = 0; i < 4; ++i) { accQ[i] = zero; accK[i] = zero; accV[i] = zero; }

  const float* xrow = x + (size_t)(row0 + l15) * 1024;
  f32x4 xx0[4], xx1[4];

  // wave wid DMA-stages frag t=wid of each matrix for tile CC into slot CC&3
#define WDMA(CC) { const int sl_ = (CC) & 3; \
    _Pragma("unroll") for (int m_ = 0; m_ < 3; ++m_) { \
      const unsigned short* gs_ = WF + ((((size_t)m_ * 32 + (CC)) * 4 + wid) * 64 + lane) * 8; \
      __builtin_amdgcn_global_load_lds( \
          (const __attribute__((address_space(1))) void*)gs_, \
          (__attribute__((address_space(3))) void*)&ldsW[sl_][(m_ * 4 + wid) * 512], \
          16, 0, 0); } }

#define PLDX(XB, C) { xx0[XB] = *(const f32x4*)(xrow + 32 * (C) + 8 * g); \
                      xx1[XB] = *(const f32x4*)(xrow + 32 * (C) + 8 * g + 4); }

  // one pipelined c-iter. KK = CC&3 (literal!), WIMM = vmcnt immediate (literal)
#define SUBIT(CC, KK, WIMM, DOW, DOX) { \
    asm volatile("s_waitcnt vmcnt(" #WIMM ")" ::: "memory"); \
    __builtin_amdgcn_s_barrier(); \
    __builtin_amdgcn_sched_barrier(0); \
    if (DOW) WDMA((CC) + 3); \
    FragU xf; \
    _Pragma("unroll") for (int i_ = 0; i_ < 4; ++i_) { \
      xf.b[i_] = (__bf16)xx0[KK][i_]; xf.b[4 + i_] = (__bf16)xx1[KK][i_]; } \
    if (DOX) PLDX(KK, (CC) + 4); \
    { const int rs_ = (CC) & 3; \
      _Pragma("unroll") for (int t = 0; t < 4; ++t) { \
        const bf16x8 wq_ = *(const bf16x8*)&ldsW[rs_][(0 * 4 + t) * 512 + lane * 8]; \
        const bf16x8 wk_ = *(const bf16x8*)&ldsW[rs_][(1 * 4 + t) * 512 + lane * 8]; \
        const bf16x8 wv_ = *(const bf16x8*)&ldsW[rs_][(2 * 4 + t) * 512 + lane * 8]; \
        accQ[t] = MFMA16(xf.b, wq_, accQ[t]); \
        accK[t] = MFMA16(xf.b, wk_, accK[t]); \
        accV[t] = MFMA16(wv_, xf.b, accV[t]); } } }

  // prologue: W tiles 0..2 in DMA flight, x chunks 0..3 in reg flight
  WDMA(0)
  __builtin_amdgcn_sched_barrier(0);
  WDMA(1) WDMA(2)
  PLDX(0, 0) PLDX(1, 1) PLDX(2, 2) PLDX(3, 3)

#pragma unroll 1
  for (int cb = 0; cb < 28; cb += 4) {
    SUBIT(cb + 0, 0, 10, 1, 1)
    SUBIT(cb + 1, 1, 10, 1, 1)
    SUBIT(cb + 2, 2, 10, 1, 1)
    SUBIT(cb + 3, 3, 10, 1, 1)
  }
  SUBIT(28, 0, 10, 1, 0)   // stages W31; no more x
  SUBIT(29, 1, 8, 0, 0)
  SUBIT(30, 2, 3, 0, 0)
  SUBIT(31, 3, 0, 0, 0)

  const int b = blockIdx.x >> 6;
  const int kt = blockIdx.x & 63;
  const int q0 = row0 & 4095;
  unsigned short* Qbase = Qb + (size_t)b * 4096 * 64;
#pragma unroll
  for (int t = 0; t < 4; ++t) {
    const int hh = 16 * t + l15;
    const float bqv = bq[hh];
#pragma unroll
    for (int r = 0; r < 4; ++r)
      Qbase[(size_t)(q0 + 4 * g + r) * 64 + hh] = bfbits((accQ[t][r] + bqv) * QSCALE);
  }
  unsigned short* KFb = KF + ((size_t)b * 64 + kt) * 4096;
  unsigned short* VFb = VF + ((size_t)b * 64 + kt) * 4096;
#pragma unroll
  for (int t = 0; t < 4; ++t) {
    const int hh = 16 * t + l15;
    const float bkv = bk[hh];
#pragma unroll
    for (int r = 0; r < 4; ++r) {
      KFb[(size_t)((wid * 2 + (t >> 1)) * 64 + (t & 1) * 32 + (l15 >> 3) * 16 + 4 * g + r) * 8 +
          (l15 & 7)] = bfbits(accK[t][r] + bkv);
      const int hv = 16 * t + 4 * g + r;
      VFb[(size_t)((t * 2 + (wid >> 1)) * 64 + (wid & 1) * 32 + (l15 >> 3) * 16 + 4 * g + r) * 8 +
          (l15 & 7)] = bfbits(accV[t][r] + bv[hv]);
    }
  }
}

// ---------------- flash attention: 32 q-rows/wave, k-split 4, K-prefetch dbuf ----------------
__global__ __launch_bounds__(256, 2) void flash_kernel(
    const unsigned short* __restrict__ Qb, const unsigned short* __restrict__ KF,
    const unsigned short* __restrict__ VF, float* __restrict__ out)
{
  __shared__ __align__(16) unsigned char lds[36864];
  const int tid = threadIdx.x;
  const int lane = tid & 63;
  const int w = tid >> 6;                 // 0..3 = k-split
  const int l15 = lane & 15;
  const int g = lane >> 4;
  const int bid = blockIdx.x;
  const int xcd = bid & 7;
  const int b = xcd >> 1;
  const int qt = (bid >> 3) * 2 + (xcd & 1);   // 0..127
  const int q0 = qt * 32;

  const unsigned short* Qp = Qb + (size_t)b * 4096 * 64;
  const unsigned short* KFb = KF + (size_t)b * 262144;
  const unsigned short* VFb = VF + (size_t)b * 262144;

  const bf16x8 qfA0 = *(const bf16x8*)(Qp + (size_t)(q0 + l15) * 64 + 8 * g);
  const bf16x8 qfA1 = *(const bf16x8*)(Qp + (size_t)(q0 + l15) * 64 + 32 + 8 * g);
  const bf16x8 qfB0 = *(const bf16x8*)(Qp + (size_t)(q0 + 16 + l15) * 64 + 8 * g);
  const bf16x8 qfB1 = *(const bf16x8*)(Qp + (size_t)(q0 + 16 + l15) * 64 + 32 + 8 * g);

  f32x4 O_A[4], O_B[4];
  const f32x4 zero = {0.f, 0.f, 0.f, 0.f};
#pragma unroll
  for (int i = 0; i < 4; ++i) { O_A[i] = zero; O_B[i] = zero; }
  float mA = -INFINITY, lA = 0.f, mB = -INFINITY, lB = 0.f;
  unsigned short* PwA = (unsigned short*)lds + (w * 2 + 0) * 1152;
  unsigned short* PwB = (unsigned short*)lds + (w * 2 + 1) * 1152;

#define SM_HALF(S, mvar, lvar, OA, PW) { \
  float mt = fmaxf(fmaxf(S[0][0], S[0][1]), fmaxf(S[0][2], S[0][3])); \
  _Pragma("unroll") for (int t = 1; t < 4; ++t) \
    _Pragma("unroll") for (int r = 0; r < 4; ++r) mt = fmaxf(mt, S[t][r]); \
  mt = fmaxf(mt, __shfl_xor(mt, 16)); \
  mt = fmaxf(mt, __shfl_xor(mt, 32)); \
  if (!__all(mt <= mvar + 8.0f)) { \
    const float mnew = fmaxf(mvar, mt); \
    const float alpha = __builtin_amdgcn_exp2f(mvar - mnew); \
    mvar = mnew; lvar *= alpha; \
    _Pragma("unroll") for (int r = 0; r < 4; ++r) { \
      const float ar = __shfl(alpha, 4 * g + r); \
      OA[0][r] *= ar; OA[1][r] *= ar; OA[2][r] *= ar; OA[3][r] *= ar; } \
  } \
  float ps = 0.f; \
  _Pragma("unroll") for (int t = 0; t < 4; ++t) { \
    const float p0 = __builtin_amdgcn_exp2f(S[t][0] - mvar); \
    const float p1 = __builtin_amdgcn_exp2f(S[t][1] - mvar); \
    const float p2 = __builtin_amdgcn_exp2f(S[t][2] - mvar); \
    const float p3 = __builtin_amdgcn_exp2f(S[t][3] - mvar); \
    ps += (p0 + p1) + (p2 + p3); \
    PackU pk_; pk_.v[0] = (__bf16)p0; pk_.v[1] = (__bf16)p1; \
    pk_.v[2] = (__bf16)p2; pk_.v[3] = (__bf16)p3; \
    *(unsigned long long*)((PW) + l15 * 72 + 16 * t + 4 * g) = pk_.q; } \
  ps += __shfl_xor(ps, 16); \
  ps += __shfl_xor(ps, 32); \
  lvar += ps; }

  // one k-tile body: load V(cur) + prefetch K(next) into KFN, then QK/softmax/PV
#define FBODY(KT, KFC, KFN, DOLD) { \
    const unsigned short* Vt_ = VFb + (KT) * 4096; \
    bf16x8 vf[8]; \
    _Pragma("unroll") for (int j = 0; j < 8; ++j) \
      vf[j] = *(const bf16x8*)(Vt_ + (j * 64 + lane) * 8); \
    if (DOLD) { \
      const unsigned short* Ktn_ = KFb + ((KT) + 4) * 4096; \
      _Pragma("unroll") for (int j = 0; j < 8; ++j) \
        KFN[j] = *(const bf16x8*)(Ktn_ + (j * 64 + lane) * 8); \
    } \
    f32x4 S_A[4], S_B[4]; \
    _Pragma("unroll") for (int t = 0; t < 4; ++t) { \
      S_A[t] = zero; \
      S_A[t] = MFMA16(KFC[2 * t], qfA0, S_A[t]); \
      S_A[t] = MFMA16(KFC[2 * t + 1], qfA1, S_A[t]); \
      S_B[t] = zero; \
      S_B[t] = MFMA16(KFC[2 * t], qfB0, S_B[t]); \
      S_B[t] = MFMA16(KFC[2 * t + 1], qfB1, S_B[t]); \
    } \
    SM_HALF(S_A, mA, lA, O_A, PwA) \
    SM_HALF(S_B, mB, lB, O_B, PwB) \
    _Pragma("unroll") for (int s = 0; s < 2; ++s) { \
      const bf16x8 paA = *(const bf16x8*)(PwA + l15 * 72 + 32 * s + 8 * g); \
      const bf16x8 paB = *(const bf16x8*)(PwB + l15 * 72 + 32 * s + 8 * g); \
      _Pragma("unroll") for (int nt = 0; nt < 4; ++nt) { \
        O_A[nt] = MFMA16(paA, vf[2 * nt + s], O_A[nt]); \
        O_B[nt] = MFMA16(paB, vf[2 * nt + s], O_B[nt]); \
      } } }

  bf16x8 kfA[8], kfB[8];
  {
    const unsigned short* Kt0 = KFb + w * 4096;
#pragma unroll
    for (int j = 0; j < 8; ++j) kfA[j] = *(const bf16x8*)(Kt0 + (j * 64 + lane) * 8);
  }
  // 16 tiles/wave, 2 bodies/iter; kt+4 always <64 in body 1 (kt <= w+56 <= 59)
#pragma unroll 1
  for (int kt = w; kt < 64; kt += 8) {
    FBODY(kt, kfA, kfB, 1)
    FBODY(kt + 4, kfB, kfA, (kt + 8 < 64))
  }

  // ---- in-LDS combine of the 4 k-split partials ----
  __syncthreads();
  float* O_l = (float*)lds;                 // [8][16][68]
  float* mlp = (float*)(lds + 34816);       // [8][16][2]
#pragma unroll
  for (int nt = 0; nt < 4; ++nt)
#pragma unroll
    for (int r = 0; r < 4; ++r) {
      O_l[((w * 2 + 0) * 16 + 4 * g + r) * 68 + 16 * nt + l15] = O_A[nt][r];
      O_l[((w * 2 + 1) * 16 + 4 * g + r) * 68 + 16 * nt + l15] = O_B[nt][r];
    }
  if (g == 0) {
    mlp[((w * 2 + 0) * 16 + l15) * 2] = mA; mlp[((w * 2 + 0) * 16 + l15) * 2 + 1] = lA;
    mlp[((w * 2 + 1) * 16 + l15) * 2] = mB; mlp[((w * 2 + 1) * 16 + l15) * 2 + 1] = lB;
  }
  __syncthreads();

  const int q = tid >> 3;           // 0..31
  const int h0 = (tid & 7) * 8;     // 0..56
  const int qh = q >> 4, qr = q & 15;
  float M = -INFINITY;
#pragma unroll
  for (int s = 0; s < 4; ++s) M = fmaxf(M, mlp[((s * 2 + qh) * 16 + qr) * 2]);
  float L = 0.f;
  f32x4 a0 = zero, a1 = zero;
#pragma unroll
  for (int s = 0; s < 4; ++s) {
    const int rowi = (s * 2 + qh) * 16 + qr;
    const float wgt = __builtin_amdgcn_exp2f(mlp[rowi * 2] - M);
    L += wgt * mlp[rowi * 2 + 1];
    const f32x4 o0 = *(const f32x4*)&O_l[rowi * 68 + h0];
    const f32x4 o1 = *(const f32x4*)&O_l[rowi * 68 + h0 + 4];
#pragma unroll
    for (int i = 0; i < 4; ++i) { a0[i] += wgt * o0[i]; a1[i] += wgt * o1[i]; }
  }
  const float inv = 1.0f / L;
  float* ob = out + ((size_t)b * 4096 + qt * 32 + q) * 64 + h0;
  f32x4 r0 = {a0[0] * inv, a0[1] * inv, a0[2] * inv, a0[3] * inv};
  f32x4 r1 = {a1[0] * inv, a1[1] * inv, a1[2] * inv, a1[3] * inv};
  *(f32x4*)ob = r0;
  *(f32x4*)(ob + 4) = r1;
}

extern "C" void kernel_launch(void* const* d_in, const int* in_sizes, int n_in,
                              void* d_out, int out_size, void* d_ws, size_t ws_size,
                              hipStream_t stream) {
  const float* x  = (const float*)d_in[0];
  const float* Wq = (const float*)d_in[1];
  const float* bq = (const float*)d_in[2];
  const float* Wk = (const float*)d_in[3];
  const float* bk = (const float*)d_in[4];
  const float* Wv = (const float*)d_in[5];
  const float* bv = (const float*)d_in[6];

  char* ws = (char*)d_ws;
  unsigned short* WF = (unsigned short*)ws;                              // 384 KB
  unsigned short* Qb = (unsigned short*)(ws + (512u << 10));             // 2 MB
  unsigned short* KF = (unsigned short*)(ws + (512u << 10) + (2u << 20));// 2 MB
  unsigned short* VF = (unsigned short*)(ws + (512u << 10) + (4u << 20));// 2 MB
  float* out = (float*)d_out;

  hipLaunchKernelGGL(wt_kernel,    dim3(96),  dim3(256), 0, stream, Wq, Wk, Wv, WF);
  hipLaunchKernelGGL(proj_kernel,  dim3(256), dim3(256), 0, stream, x, WF, bq, bk, bv, Qb, KF, VF);
  hipLaunchKernelGGL(flash_kernel, dim3(512), dim3(256), 0, stream, Qb, KF, VF, out);
}

// Round 16
// 55.071 us; speedup vs baseline: 1.0578x; 1.0016x over previous
//
#include <hip/hip_runtime.h>

typedef __bf16 bf16x8 __attribute__((ext_vector_type(8)));
typedef __bf16 bf16x4 __attribute__((ext_vector_type(4)));
typedef float f32x4 __attribute__((ext_vector_type(4)));
typedef unsigned short u16x8 __attribute__((ext_vector_type(8)));

union FragU { u16x8 u; bf16x8 b; };
union PackU { bf16x4 v; unsigned long long q; };

__device__ __forceinline__ unsigned short bfbits(float f) {
  __bf16 h = (__bf16)f;
  union { __bf16 h; unsigned short s; } cv; cv.h = h;
  return cv.s;
}

#define MFMA16(a, b, c) __builtin_amdgcn_mfma_f32_16x16x32_bf16((a), (b), (c), 0, 0, 0)

// 0.125 (1/sqrt(64)) * log2(e): softmax done in base-2
#define QSCALE 0.18033688011112042f

// ---------------- W -> fragment-order bf16: WF[m][c][t][lane][8] ----------------
__global__ __launch_bounds__(256) void wt_kernel(
    const float* __restrict__ Wq, const float* __restrict__ Wk, const float* __restrict__ Wv,
    unsigned short* __restrict__ WF)
{
  const int m = blockIdx.x >> 5;         // 0..2
  const int c = blockIdx.x & 31;         // 0..31
  const float* W = (m == 0) ? Wq : ((m == 1) ? Wk : Wv);
  const int t = threadIdx.x >> 6;
  const int lane = threadIdx.x & 63;
  const int l15 = lane & 15;
  const int g = lane >> 4;
  unsigned short* dst = WF + ((((size_t)m * 32 + c) * 4 + t) * 64 + lane) * 8;
#pragma unroll
  for (int e = 0; e < 8; ++e)
    dst[e] = bfbits(W[(size_t)(32 * c + 8 * g + e) * 64 + (16 * t + l15)]);
}

// ---------------- fused QKV projection: counted-vmcnt pipelined W-DMA (R13-proven) ----------------
__global__ __launch_bounds__(256, 1) void proj_kernel(
    const float* __restrict__ x, const unsigned short* __restrict__ WF,
    const float* __restrict__ bq, const float* __restrict__ bk, const float* __restrict__ bv,
    unsigned short* __restrict__ Qb, unsigned short* __restrict__ KF,
    unsigned short* __restrict__ VF)
{
  __shared__ __align__(16) unsigned short ldsW[4][6144];   // 4 slots x 12 KB = 48 KB
  const int tid = threadIdx.x;
  const int lane = tid & 63;
  const int wid = tid >> 6;               // 0..3
  const int l15 = lane & 15;
  const int g = lane >> 4;
  const int row0 = blockIdx.x * 64 + wid * 16;

  f32x4 accQ[4], accK[4], accV[4];
  const f32x4 zero = {0.f, 0.f, 0.f, 0.f};
#pragma unroll
  for (int i = 0; i < 4; ++i) { accQ[i] = zero; accK[i] = zero; accV[i] = zero; }

  const float* xrow = x + (size_t)(row0 + l15) * 1024;
  f32x4 xx0[4], xx1[4];

  // wave wid DMA-stages frag t=wid of each matrix for tile CC into slot CC&3
#define WDMA(CC) { const int sl_ = (CC) & 3; \
    _Pragma("unroll") for (int m_ = 0; m_ < 3; ++m_) { \
      const unsigned short* gs_ = WF + ((((size_t)m_ * 32 + (CC)) * 4 + wid) * 64 + lane) * 8; \
      __builtin_amdgcn_global_load_lds( \
          (const __attribute__((address_space(1))) void*)gs_, \
          (__attribute__((address_space(3))) void*)&ldsW[sl_][(m_ * 4 + wid) * 512], \
          16, 0, 0); } }

#define PLDX(XB, C) { xx0[XB] = *(const f32x4*)(xrow + 32 * (C) + 8 * g); \
                      xx1[XB] = *(const f32x4*)(xrow + 32 * (C) + 8 * g + 4); }

  // one pipelined c-iter. KK = CC&3 (literal!), WIMM = vmcnt immediate (literal)
#define SUBIT(CC, KK, WIMM, DOW, DOX) { \
    asm volatile("s_waitcnt vmcnt(" #WIMM ")" ::: "memory"); \
    __builtin_amdgcn_s_barrier(); \
    __builtin_amdgcn_sched_barrier(0); \
    if (DOW) WDMA((CC) + 3); \
    FragU xf; \
    _Pragma("unroll") for (int i_ = 0; i_ < 4; ++i_) { \
      xf.b[i_] = (__bf16)xx0[KK][i_]; xf.b[4 + i_] = (__bf16)xx1[KK][i_]; } \
    if (DOX) PLDX(KK, (CC) + 4); \
    { const int rs_ = (CC) & 3; \
      _Pragma("unroll") for (int t = 0; t < 4; ++t) { \
        const bf16x8 wq_ = *(const bf16x8*)&ldsW[rs_][(0 * 4 + t) * 512 + lane * 8]; \
        const bf16x8 wk_ = *(const bf16x8*)&ldsW[rs_][(1 * 4 + t) * 512 + lane * 8]; \
        const bf16x8 wv_ = *(const bf16x8*)&ldsW[rs_][(2 * 4 + t) * 512 + lane * 8]; \
        accQ[t] = MFMA16(xf.b, wq_, accQ[t]); \
        accK[t] = MFMA16(xf.b, wk_, accK[t]); \
        accV[t] = MFMA16(wv_, xf.b, accV[t]); } } }

  // prologue: W tiles 0..2 in DMA flight, x chunks 0..3 in reg flight
  WDMA(0)
  __builtin_amdgcn_sched_barrier(0);
  WDMA(1) WDMA(2)
  PLDX(0, 0) PLDX(1, 1) PLDX(2, 2) PLDX(3, 3)

#pragma unroll 1
  for (int cb = 0; cb < 28; cb += 4) {
    SUBIT(cb + 0, 0, 10, 1, 1)
    SUBIT(cb + 1, 1, 10, 1, 1)
    SUBIT(cb + 2, 2, 10, 1, 1)
    SUBIT(cb + 3, 3, 10, 1, 1)
  }
  SUBIT(28, 0, 10, 1, 0)   // stages W31; no more x
  SUBIT(29, 1, 8, 0, 0)
  SUBIT(30, 2, 3, 0, 0)
  SUBIT(31, 3, 0, 0, 0)

  const int b = blockIdx.x >> 6;
  const int kt = blockIdx.x & 63;
  const int q0 = row0 & 4095;
  unsigned short* Qbase = Qb + (size_t)b * 4096 * 64;
#pragma unroll
  for (int t = 0; t < 4; ++t) {
    const int hh = 16 * t + l15;
    const float bqv = bq[hh];
#pragma unroll
    for (int r = 0; r < 4; ++r)
      Qbase[(size_t)(q0 + 4 * g + r) * 64 + hh] = bfbits((accQ[t][r] + bqv) * QSCALE);
  }
  unsigned short* KFb = KF + ((size_t)b * 64 + kt) * 4096;
  unsigned short* VFb = VF + ((size_t)b * 64 + kt) * 4096;
#pragma unroll
  for (int t = 0; t < 4; ++t) {
    const int hh = 16 * t + l15;
    const float bkv = bk[hh];
#pragma unroll
    for (int r = 0; r < 4; ++r) {
      KFb[(size_t)((wid * 2 + (t >> 1)) * 64 + (t & 1) * 32 + (l15 >> 3) * 16 + 4 * g + r) * 8 +
          (l15 & 7)] = bfbits(accK[t][r] + bkv);
      const int hv = 16 * t + 4 * g + r;
      VFb[(size_t)((t * 2 + (wid >> 1)) * 64 + (wid & 1) * 32 + (l15 >> 3) * 16 + 4 * g + r) * 8 +
          (l15 & 7)] = bfbits(accV[t][r] + bv[hv]);
    }
  }
}

// ---------------- flash attention: 64 q-rows/block, wave-paired k-streams ----------------
// grid 256 = XCD-swizzled (4 batches x 64 q-blocks of 64 rows); block 512 thr = 8 waves.
// wave w: qg = w>>2 (32-row group), ks = w&3 (k-split). The two waves with equal ks
// read IDENTICAL K/V tile streams on the same CU -> second reader hits L1, halving
// L2 traffic vs R15's 8 distinct streams. Per-wave body identical to R15 (kf dbuf).
__global__ __launch_bounds__(512, 2) void flash_kernel(
    const unsigned short* __restrict__ Qb, const unsigned short* __restrict__ KF,
    const unsigned short* __restrict__ VF, float* __restrict__ out)
{
  __shared__ __align__(16) unsigned char lds[36864];
  const int tid = threadIdx.x;
  const int lane = tid & 63;
  const int w = tid >> 6;                 // 0..7
  const int qg = w >> 2;                  // 0..1: 32-row group
  const int ks = w & 3;                   // k-split
  const int l15 = lane & 15;
  const int g = lane >> 4;
  const int bid = blockIdx.x;
  const int xcd = bid & 7;
  const int b = xcd >> 1;
  const int qt = (bid >> 3) * 2 + (xcd & 1);   // 0..63 (64-row tiles)
  const int q0 = qt * 64 + qg * 32;

  const unsigned short* Qp = Qb + (size_t)b * 4096 * 64;
  const unsigned short* KFb = KF + (size_t)b * 262144;
  const unsigned short* VFb = VF + (size_t)b * 262144;

  const bf16x8 qfA0 = *(const bf16x8*)(Qp + (size_t)(q0 + l15) * 64 + 8 * g);
  const bf16x8 qfA1 = *(const bf16x8*)(Qp + (size_t)(q0 + l15) * 64 + 32 + 8 * g);
  const bf16x8 qfB0 = *(const bf16x8*)(Qp + (size_t)(q0 + 16 + l15) * 64 + 8 * g);
  const bf16x8 qfB1 = *(const bf16x8*)(Qp + (size_t)(q0 + 16 + l15) * 64 + 32 + 8 * g);

  f32x4 O_A[4], O_B[4];
  const f32x4 zero = {0.f, 0.f, 0.f, 0.f};
#pragma unroll
  for (int i = 0; i < 4; ++i) { O_A[i] = zero; O_B[i] = zero; }
  float mA = -INFINITY, lA = 0.f, mB = -INFINITY, lB = 0.f;
  unsigned short* PwA = (unsigned short*)lds + (w * 2 + 0) * 1152;
  unsigned short* PwB = (unsigned short*)lds + (w * 2 + 1) * 1152;

#define SM_HALF(S, mvar, lvar, OA, PW) { \
  float mt = fmaxf(fmaxf(S[0][0], S[0][1]), fmaxf(S[0][2], S[0][3])); \
  _Pragma("unroll") for (int t = 1; t < 4; ++t) \
    _Pragma("unroll") for (int r = 0; r < 4; ++r) mt = fmaxf(mt, S[t][r]); \
  mt = fmaxf(mt, __shfl_xor(mt, 16)); \
  mt = fmaxf(mt, __shfl_xor(mt, 32)); \
  if (!__all(mt <= mvar + 8.0f)) { \
    const float mnew = fmaxf(mvar, mt); \
    const float alpha = __builtin_amdgcn_exp2f(mvar - mnew); \
    mvar = mnew; lvar *= alpha; \
    _Pragma("unroll") for (int r = 0; r < 4; ++r) { \
      const float ar = __shfl(alpha, 4 * g + r); \
      OA[0][r] *= ar; OA[1][r] *= ar; OA[2][r] *= ar; OA[3][r] *= ar; } \
  } \
  float ps = 0.f; \
  _Pragma("unroll") for (int t = 0; t < 4; ++t) { \
    const float p0 = __builtin_amdgcn_exp2f(S[t][0] - mvar); \
    const float p1 = __builtin_amdgcn_exp2f(S[t][1] - mvar); \
    const float p2 = __builtin_amdgcn_exp2f(S[t][2] - mvar); \
    const float p3 = __builtin_amdgcn_exp2f(S[t][3] - mvar); \
    ps += (p0 + p1) + (p2 + p3); \
    PackU pk_; pk_.v[0] = (__bf16)p0; pk_.v[1] = (__bf16)p1; \
    pk_.v[2] = (__bf16)p2; pk_.v[3] = (__bf16)p3; \
    *(unsigned long long*)((PW) + l15 * 72 + 16 * t + 4 * g) = pk_.q; } \
  ps += __shfl_xor(ps, 16); \
  ps += __shfl_xor(ps, 32); \
  lvar += ps; }

  // one k-tile body: load V(cur) + prefetch K(next) into KFN, then QK/softmax/PV
#define FBODY(KT, KFC, KFN, DOLD) { \
    const unsigned short* Vt_ = VFb + (KT) * 4096; \
    bf16x8 vf[8]; \
    _Pragma("unroll") for (int j = 0; j < 8; ++j) \
      vf[j] = *(const bf16x8*)(Vt_ + (j * 64 + lane) * 8); \
    if (DOLD) { \
      const unsigned short* Ktn_ = KFb + ((KT) + 4) * 4096; \
      _Pragma("unroll") for (int j = 0; j < 8; ++j) \
        KFN[j] = *(const bf16x8*)(Ktn_ + (j * 64 + lane) * 8); \
    } \
    f32x4 S_A[4], S_B[4]; \
    _Pragma("unroll") for (int t = 0; t < 4; ++t) { \
      S_A[t] = zero; \
      S_A[t] = MFMA16(KFC[2 * t], qfA0, S_A[t]); \
      S_A[t] = MFMA16(KFC[2 * t + 1], qfA1, S_A[t]); \
      S_B[t] = zero; \
      S_B[t] = MFMA16(KFC[2 * t], qfB0, S_B[t]); \
      S_B[t] = MFMA16(KFC[2 * t + 1], qfB1, S_B[t]); \
    } \
    SM_HALF(S_A, mA, lA, O_A, PwA) \
    SM_HALF(S_B, mB, lB, O_B, PwB) \
    _Pragma("unroll") for (int s = 0; s < 2; ++s) { \
      const bf16x8 paA = *(const bf16x8*)(PwA + l15 * 72 + 32 * s + 8 * g); \
      const bf16x8 paB = *(const bf16x8*)(PwB + l15 * 72 + 32 * s + 8 * g); \
      _Pragma("unroll") for (int nt = 0; nt < 4; ++nt) { \
        O_A[nt] = MFMA16(paA, vf[2 * nt + s], O_A[nt]); \
        O_B[nt] = MFMA16(paB, vf[2 * nt + s], O_B[nt]); \
      } } }

  bf16x8 kfA[8], kfB[8];
  {
    const unsigned short* Kt0 = KFb + ks * 4096;
#pragma unroll
    for (int j = 0; j < 8; ++j) kfA[j] = *(const bf16x8*)(Kt0 + (j * 64 + lane) * 8);
  }
  // 16 tiles/wave, 2 bodies/iter; kt+4 always <64 in body 1 (kt <= ks+56 <= 59)
#pragma unroll 1
  for (int kt = ks; kt < 64; kt += 8) {
    FBODY(kt, kfA, kfB, 1)
    FBODY(kt + 4, kfB, kfA, (kt + 8 < 64))
  }

  // ---- two-pass in-LDS combine: 4 ks-partials per 16-row half, per 32-row group ----
  float* O_l = (float*)lds;                 // [8][16][68] = 34816 B
  float* mlp = (float*)(lds + 34816);       // [8][16][2]  = 1024 B
  const int q = tid >> 4;            // 0..31
  const int h0 = (tid & 15) * 4;     // 0..60
  const int qh = q >> 4, qr = q & 15;

#pragma unroll 1
  for (int pass = 0; pass < 2; ++pass) {
    __syncthreads();                 // P reads done (pass0) / prior combine done (pass1)
    if (qg == pass) {
#pragma unroll
      for (int nt = 0; nt < 4; ++nt)
#pragma unroll
        for (int r = 0; r < 4; ++r) {
          O_l[((ks * 2 + 0) * 16 + 4 * g + r) * 68 + 16 * nt + l15] = O_A[nt][r];
          O_l[((ks * 2 + 1) * 16 + 4 * g + r) * 68 + 16 * nt + l15] = O_B[nt][r];
        }
      if (g == 0) {
        mlp[((ks * 2 + 0) * 16 + l15) * 2] = mA; mlp[((ks * 2 + 0) * 16 + l15) * 2 + 1] = lA;
        mlp[((ks * 2 + 1) * 16 + l15) * 2] = mB; mlp[((ks * 2 + 1) * 16 + l15) * 2 + 1] = lB;
      }
    }
    __syncthreads();
    float M = -INFINITY;
#pragma unroll
    for (int s = 0; s < 4; ++s) M = fmaxf(M, mlp[((s * 2 + qh) * 16 + qr) * 2]);
    float L = 0.f;
    f32x4 a0 = zero;
#pragma unroll
    for (int s = 0; s < 4; ++s) {
      const int rowi = (s * 2 + qh) * 16 + qr;
      const float wgt = __builtin_amdgcn_exp2f(mlp[rowi * 2] - M);
      L += wgt * mlp[rowi * 2 + 1];
      const f32x4 o0 = *(const f32x4*)&O_l[rowi * 68 + h0];
#pragma unroll
      for (int i = 0; i < 4; ++i) a0[i] += wgt * o0[i];
    }
    const float inv = 1.0f / L;
    float* ob = out + ((size_t)b * 4096 + qt * 64 + pass * 32 + q) * 64 + h0;
    f32x4 r0 = {a0[0] * inv, a0[1] * inv, a0[2] * inv, a0[3] * inv};
    *(f32x4*)ob = r0;
  }
}

extern "C" void kernel_launch(void* const* d_in, const int* in_sizes, int n_in,
                              void* d_out, int out_size, void* d_ws, size_t ws_size,
                              hipStream_t stream) {
  const float* x  = (const float*)d_in[0];
  const float* Wq = (const float*)d_in[1];
  const float* bq = (const float*)d_in[2];
  const float* Wk = (const float*)d_in[3];
  const float* bk = (const float*)d_in[4];
  const float* Wv = (const float*)d_in[5];
  const float* bv = (const float*)d_in[6];

  char* ws = (char*)d_ws;
  unsigned short* WF = (unsigned short*)ws;                              // 384 KB
  unsigned short* Qb = (unsigned short*)(ws + (512u << 10));             // 2 MB
  unsigned short* KF = (unsigned short*)(ws + (512u << 10) + (2u << 20));// 2 MB
  unsigned short* VF = (unsigned short*)(ws + (512u << 10) + (4u << 20));// 2 MB
  float* out = (float*)d_out;

  hipLaunchKernelGGL(wt_kernel,    dim3(96),  dim3(256), 0, stream, Wq, Wk, Wv, WF);
  hipLaunchKernelGGL(proj_kernel,  dim3(256), dim3(256), 0, stream, x, WF, bq, bk, bv, Qb, KF, VF);
  hipLaunchKernelGGL(flash_kernel, dim3(256), dim3(512), 0, stream, Qb, KF, VF, out);
}